// Round 6
// baseline (125.697 us; speedup 1.0000x reference)
//
#include <hip/hip_runtime.h>

// msg[b,o,n] = sum_d We[o,d]*e_vw[b,d,n] + sum_d Ww[o,d]*h_w[b,d,n] + be[o]+bw[o]
// B=128, D=768, N=256. Fused GEMM per batch: M=768, N=256, K=1536.
// Tile 192x256, BK=64, 512 thr = 8 waves (2m x 4n), wave tile 96x64,
// acc[6][4] f32x4 = 96 regs. 2-phase template schedule per K-step:
// {frag reads + store(t+1) + issue(t+2) ; barrier ; lgkm(0) ; 24 MFMA} x2.
// A pre-packed bf16 fragments (prep kernel, L2-resident); B reg-staged fp32->bf16.
// Grid 512 = 4 m-tiles x 128 batches; all 4 m-blocks of a batch on one XCD.

#define DD   768
#define NCOL 256
#define KTOT 1536
#define BM   192
#define BN   256
#define BK   64
#define NIT  24

typedef __bf16 bf16;
typedef __attribute__((ext_vector_type(8))) __bf16 bf16x8;
typedef __attribute__((ext_vector_type(4))) float f32x4;
typedef __attribute__((ext_vector_type(4))) unsigned int u32x4;

// 128B rows. XOR row^(row>>3) bits into 16B-slot bits: frag reads (16
// consecutive rows, same 16B col) -> 2-way (free); scattered writes -> spread.
__device__ __forceinline__ int swz(int row, int kb) {
  return row * 128 + (kb ^ (((row ^ (row >> 3)) & 7) << 4));
}

// ---- prep: Wtile chunks of 16B: i = ((T*4+mt)*3+c)*512 + t ->
//      o = mt*192 + c*64 + (t>>3), k = T*64 + (t&7)*8 ; k<768 We else Ww ----
__global__ void prep_w(const float* __restrict__ We, const float* __restrict__ Ww,
                       unsigned short* __restrict__ Wtile) {
  int i = blockIdx.x * blockDim.x + threadIdx.x;  // 147456 chunks
  int t = i & 511;
  int g = i >> 9;
  int c = g % 3;
  int h = g / 3;
  int mt = h & 3, T = h >> 2;
  int o = mt * 192 + c * 64 + (t >> 3);
  int k = T * 64 + (t & 7) * 8;
  const float* src = (k < DD) ? (We + (size_t)o * DD + k)
                              : (Ww + (size_t)o * DD + (k - DD));
  f32x4 v0 = *(const f32x4*)src;
  f32x4 v1 = *(const f32x4*)(src + 4);
  union { bf16 h8[8]; u32x4 q; } u;
  u.h8[0]=(bf16)v0[0]; u.h8[1]=(bf16)v0[1]; u.h8[2]=(bf16)v0[2]; u.h8[3]=(bf16)v0[3];
  u.h8[4]=(bf16)v1[0]; u.h8[5]=(bf16)v1[1]; u.h8[6]=(bf16)v1[2]; u.h8[7]=(bf16)v1[3];
  *(u32x4*)(Wtile + (size_t)i * 8) = u.q;
}

__global__ __launch_bounds__(512, 2)
void msg_kernel(const float* __restrict__ h_w, const float* __restrict__ e_vw,
                const unsigned short* __restrict__ Wtile,
                const float* __restrict__ be, const float* __restrict__ bw,
                float* __restrict__ out) {
  // buf: A 24576 + B 32768 = 57344 each; bias at 114688
  __shared__ __align__(16) unsigned char smem[2 * 57344 + 768];
  float* bias_s = (float*)(smem + 114688);

  const int tid = threadIdx.x;
  // XCD map: xcd = p&7 owns batches xcd*16..+15; 4 m-blocks of a batch are
  // consecutive slots on the same XCD -> X[b] L2 reuse.
  const int p = blockIdx.x;
  const int slot = p >> 3;
  const int bb = (p & 7) * 16 + (slot >> 2);
  const int mt = slot & 3;
  const int bm0 = mt * 192;

  if (tid < 192) bias_s[tid] = be[bm0 + tid] + bw[bm0 + tid];

  // ---- A staging: 3 chunks/thread, row = c*64 + (tid>>3), kb = (tid&7)*16 ----
  const unsigned short* pA = Wtile + (size_t)(mt * 3) * 4096 + (size_t)tid * 8;
  const int rA = tid >> 3, kA = (tid & 7) * 16;
  int wAo[3];
  #pragma unroll
  for (int c = 0; c < 3; ++c) wAo[c] = swz(c * 64 + rA, kA);

  // ---- B staging: thread = (nq = tid&63 -> 4 cols, kk = tid>>6 -> 8 k) ----
  const int nq = tid & 63, kk = tid >> 6;
  const size_t xofs = (size_t)bb * DD * NCOL + (size_t)(kk * 8) * NCOL + nq * 4;
  const float* pE = e_vw + xofs;
  const float* pH = h_w + xofs;
  int wBo[4];
  #pragma unroll
  for (int j = 0; j < 4; ++j) wBo[j] = swz(4 * nq + j, kk * 16);

  u32x4 aR[3];   // A prefetch (bf16 bits)
  f32x4 bR[8];   // B prefetch (fp32, 4 cols x 8 k)

  auto issueA = [&](int T) {
    const unsigned short* q = pA + (size_t)T * 49152;
    aR[0] = *(const u32x4*)q;
    aR[1] = *(const u32x4*)(q + 4096);
    aR[2] = *(const u32x4*)(q + 8192);
  };
  auto issueB = [&](int T) {
    const float* q = (T < 12) ? (pE + (size_t)T * BK * NCOL)
                              : (pH + (size_t)(T - 12) * BK * NCOL);
    #pragma unroll
    for (int i = 0; i < 8; ++i) bR[i] = *(const f32x4*)(q + (size_t)i * NCOL);
  };
  auto storeA = [&](int buf) {
    unsigned char* base = smem + buf * 57344;
    #pragma unroll
    for (int c = 0; c < 3; ++c) *(u32x4*)(base + wAo[c]) = aR[c];
  };
  auto storeB = [&](int buf) {
    unsigned char* base = smem + buf * 57344 + 24576;
    #pragma unroll
    for (int j = 0; j < 4; ++j) {
      union { bf16 h8[8]; u32x4 q; } u;
      #pragma unroll
      for (int i = 0; i < 8; ++i) u.h8[i] = (bf16)bR[i][j];
      *(u32x4*)(base + wBo[j]) = u.q;
    }
  };

  // ---- compute map: 8 waves = 2m x 4n, wave tile 96x64 ----
  const int lane = tid & 63, wid = tid >> 6;
  const int wm = wid >> 2, wn = wid & 3;
  const int lr = lane & 15, qk = (lane >> 4) * 16;
  f32x4 acc[6][4] = {};

  // ---- prologue: stage tile 0, leave tile 1 in regs/flight ----
  issueA(0); issueB(0);
  storeA(0); storeB(0);
  issueA(1); issueB(1);
  asm volatile("s_waitcnt lgkmcnt(0)" ::: "memory");
  __builtin_amdgcn_s_barrier();

  for (int t = 0; t < NIT; ++t) {
    const int c = t & 1;
    const unsigned char* bA = smem + c * 57344;
    const unsigned char* bB = bA + 24576;
    bf16x8 af[6], bfv[4];

    // ===== phase 0 (ks=0): reads ; storeA(t+1) ; issueA(t+2) ; bar ; MFMA =====
    #pragma unroll
    for (int m = 0; m < 6; ++m)
      af[m] = *(const bf16x8*)(bA + swz(wm * 96 + m * 16 + lr, qk));
    #pragma unroll
    for (int n = 0; n < 4; ++n)
      bfv[n] = *(const bf16x8*)(bB + swz(wn * 64 + n * 16 + lr, qk));
    if (t < NIT - 1) storeA(c ^ 1);       // tile t+1 (aR issued at t-1)
    if (t < NIT - 2) issueA(t + 2);       // refill aR
    __builtin_amdgcn_s_barrier();
    asm volatile("s_waitcnt lgkmcnt(0)" ::: "memory");
    __builtin_amdgcn_sched_barrier(0);
    __builtin_amdgcn_s_setprio(1);
    #pragma unroll
    for (int m = 0; m < 6; ++m)
      #pragma unroll
      for (int n = 0; n < 4; ++n)
        acc[m][n] = __builtin_amdgcn_mfma_f32_16x16x32_bf16(af[m], bfv[n], acc[m][n], 0, 0, 0);
    __builtin_amdgcn_s_setprio(0);

    // ===== phase 1 (ks=1): reads ; storeB(t+1) ; issueB(t+2) ; bar ; MFMA =====
    #pragma unroll
    for (int m = 0; m < 6; ++m)
      af[m] = *(const bf16x8*)(bA + swz(wm * 96 + m * 16 + lr, 64 + qk));
    #pragma unroll
    for (int n = 0; n < 4; ++n)
      bfv[n] = *(const bf16x8*)(bB + swz(wn * 64 + n * 16 + lr, 64 + qk));
    if (t < NIT - 1) storeB(c ^ 1);       // tile t+1 (bR issued at t-1, cvt here)
    if (t < NIT - 2) issueB(t + 2);       // refill bR
    __builtin_amdgcn_s_barrier();
    asm volatile("s_waitcnt lgkmcnt(0)" ::: "memory");
    __builtin_amdgcn_sched_barrier(0);
    __builtin_amdgcn_s_setprio(1);
    #pragma unroll
    for (int m = 0; m < 6; ++m)
      #pragma unroll
      for (int n = 0; n < 4; ++n)
        acc[m][n] = __builtin_amdgcn_mfma_f32_16x16x32_bf16(af[m], bfv[n], acc[m][n], 0, 0, 0);
    __builtin_amdgcn_s_setprio(0);

    // step-end: make this step's LDS writes visible before next step's reads
    asm volatile("s_waitcnt lgkmcnt(0)" ::: "memory");
    __builtin_amdgcn_s_barrier();
  }

  // ---- epilogue: bias + store. C/D: col=lane&15, row=(lane>>4)*4+reg ----
  float* po = out + (size_t)bb * DD * NCOL;
  const int g4 = (lane >> 4) * 4;
  #pragma unroll
  for (int m = 0; m < 6; ++m) {
    const int r0 = wm * 96 + m * 16 + g4;
    #pragma unroll
    for (int n = 0; n < 4; ++n) {
      const int col = wn * 64 + n * 16 + lr;
      #pragma unroll
      for (int j = 0; j < 4; ++j)
        po[(size_t)(bm0 + r0 + j) * NCOL + col] = acc[m][n][j] + bias_s[r0 + j];
    }
  }
}

extern "C" void kernel_launch(void* const* d_in, const int* in_sizes, int n_in,
                              void* d_out, int out_size, void* d_ws, size_t ws_size,
                              hipStream_t stream) {
  // inputs: 0:h_v(unused) 1:h_w 2:e_vw 3:We 4:be 5:Ww 6:bw
  const float* h_w  = (const float*)d_in[1];
  const float* e_vw = (const float*)d_in[2];
  const float* We   = (const float*)d_in[3];
  const float* be   = (const float*)d_in[4];
  const float* Ww   = (const float*)d_in[5];
  const float* bw   = (const float*)d_in[6];
  float* out = (float*)d_out;
  unsigned short* Wtile = (unsigned short*)d_ws;  // 147456 x 16B = 2.36 MB

  prep_w<<<dim3(576), 256, 0, stream>>>(We, Ww, Wtile);
  msg_kernel<<<dim3(512), 512, 0, stream>>>(h_w, e_vw, Wtile, be, bw, out);
}

// Round 7
// 109.892 us; speedup vs baseline: 1.1438x; 1.1438x over previous
//
#include <hip/hip_runtime.h>

// msg[b,o,n] = sum_d We[o,d]*e_vw[b,d,n] + sum_d Ww[o,d]*h_w[b,d,n] + be[o]+bw[o]
// B=128, D=768, N=256. Fused GEMM per batch: M=768, N=256, K=1536.
// Tile 192x256, BK=64, 512 thr = 8 waves (2m x 4n), wave tile 96x64.
// ONE barrier per K-step (lgkm-only drain); NO sched_barrier/setprio pinning:
// compiler interleaves ds_reads with MFMAs using counted lgkmcnt (m97 evidence),
// global prefetch (depth 2) survives barriers with counted vmcnt at consumption.
// A pre-packed bf16 fragments (prep kernel, L2-resident); B reg-staged fp32->bf16.

#define DD   768
#define NCOL 256
#define KTOT 1536
#define BM   192
#define BN   256
#define BK   64
#define NIT  24

typedef __bf16 bf16;
typedef __attribute__((ext_vector_type(8))) __bf16 bf16x8;
typedef __attribute__((ext_vector_type(4))) float f32x4;
typedef __attribute__((ext_vector_type(4))) unsigned int u32x4;

// 128B rows. XOR row^(row>>3) bits into 16B-slot bits: frag reads and staged
// writes both land 2-way max per 16-lane group (optimal for b128).
__device__ __forceinline__ int swz(int row, int kb) {
  return row * 128 + (kb ^ (((row ^ (row >> 3)) & 7) << 4));
}

// ---- prep: Wtile chunks of 16B: i = ((T*4+mt)*3+c)*512 + t ->
//      o = mt*192 + c*64 + (t>>3), k = T*64 + (t&7)*8 ; k<768 We else Ww ----
__global__ void prep_w(const float* __restrict__ We, const float* __restrict__ Ww,
                       unsigned short* __restrict__ Wtile) {
  int i = blockIdx.x * blockDim.x + threadIdx.x;  // 147456 chunks
  int t = i & 511;
  int g = i >> 9;
  int c = g % 3;
  int h = g / 3;
  int mt = h & 3, T = h >> 2;
  int o = mt * 192 + c * 64 + (t >> 3);
  int k = T * 64 + (t & 7) * 8;
  const float* src = (k < DD) ? (We + (size_t)o * DD + k)
                              : (Ww + (size_t)o * DD + (k - DD));
  f32x4 v0 = *(const f32x4*)src;
  f32x4 v1 = *(const f32x4*)(src + 4);
  union { bf16 h8[8]; u32x4 q; } u;
  u.h8[0]=(bf16)v0[0]; u.h8[1]=(bf16)v0[1]; u.h8[2]=(bf16)v0[2]; u.h8[3]=(bf16)v0[3];
  u.h8[4]=(bf16)v1[0]; u.h8[5]=(bf16)v1[1]; u.h8[6]=(bf16)v1[2]; u.h8[7]=(bf16)v1[3];
  *(u32x4*)(Wtile + (size_t)i * 8) = u.q;
}

__global__ __launch_bounds__(512, 2)
void msg_kernel(const float* __restrict__ h_w, const float* __restrict__ e_vw,
                const unsigned short* __restrict__ Wtile,
                const float* __restrict__ be, const float* __restrict__ bw,
                float* __restrict__ out) {
  // buf: A 24576 + B 32768 = 57344 each; bias at 114688
  __shared__ __align__(16) unsigned char smem[2 * 57344 + 768];
  float* bias_s = (float*)(smem + 114688);

  const int tid = threadIdx.x;
  // XCD map: xcd = p&7 owns batches xcd*16..+15; 4 m-blocks of a batch are
  // consecutive slots on the same XCD -> X[b] L2 reuse.
  const int p = blockIdx.x;
  const int slot = p >> 3;
  const int bb = (p & 7) * 16 + (slot >> 2);
  const int mt = slot & 3;
  const int bm0 = mt * 192;

  if (tid < 192) bias_s[tid] = be[bm0 + tid] + bw[bm0 + tid];

  // ---- A staging: 3 chunks/thread, row = c*64 + (tid>>3), kb = (tid&7)*16 ----
  const unsigned short* pA = Wtile + (size_t)(mt * 3) * 4096 + (size_t)tid * 8;
  const int rA = tid >> 3, kA = (tid & 7) * 16;
  int wAo[3];
  #pragma unroll
  for (int c = 0; c < 3; ++c) wAo[c] = swz(c * 64 + rA, kA);

  // ---- B staging: thread = (nq = tid&63 -> 4 cols, kk = tid>>6 -> 8 k) ----
  const int nq = tid & 63, kk = tid >> 6;
  const size_t xofs = (size_t)bb * DD * NCOL + (size_t)(kk * 8) * NCOL + nq * 4;
  const float* pE = e_vw + xofs;
  const float* pH = h_w + xofs;
  int wBo[4];
  #pragma unroll
  for (int j = 0; j < 4; ++j) wBo[j] = swz(4 * nq + j, kk * 16);

  u32x4 aR[3];   // A prefetch (bf16 bits)
  f32x4 bR[8];   // B prefetch (fp32, 4 cols x 8 k)

  auto issueA = [&](int T) {
    const unsigned short* q = pA + (size_t)T * 49152;
    aR[0] = *(const u32x4*)q;
    aR[1] = *(const u32x4*)(q + 4096);
    aR[2] = *(const u32x4*)(q + 8192);
  };
  auto issueB = [&](int T) {
    const float* q = (T < 12) ? (pE + (size_t)T * BK * NCOL)
                              : (pH + (size_t)(T - 12) * BK * NCOL);
    #pragma unroll
    for (int i = 0; i < 8; ++i) bR[i] = *(const f32x4*)(q + (size_t)i * NCOL);
  };
  auto storeA = [&](int buf) {
    unsigned char* base = smem + buf * 57344;
    #pragma unroll
    for (int c = 0; c < 3; ++c) *(u32x4*)(base + wAo[c]) = aR[c];
  };
  auto storeB = [&](int buf) {
    unsigned char* base = smem + buf * 57344 + 24576;
    #pragma unroll
    for (int j = 0; j < 4; ++j) {
      union { bf16 h8[8]; u32x4 q; } u;
      #pragma unroll
      for (int i = 0; i < 8; ++i) u.h8[i] = (bf16)bR[i][j];
      *(u32x4*)(base + wBo[j]) = u.q;
    }
  };

  // ---- compute map: 8 waves = 2m x 4n, wave tile 96x64 ----
  const int lane = tid & 63, wid = tid >> 6;
  const int wm = wid >> 2, wn = wid & 3;
  const int lr = lane & 15, qk = (lane >> 4) * 16;
  f32x4 acc[6][4] = {};

  // ---- prologue: stage tile 0, leave tile 1 in regs/flight ----
  issueA(0); issueB(0);
  storeA(0); storeB(0);
  issueA(1); issueB(1);
  asm volatile("s_waitcnt lgkmcnt(0)" ::: "memory");
  __builtin_amdgcn_s_barrier();

  // ---- main loop: ONE barrier per K-step; compiler schedules the interior ----
  for (int t = 0; t < NIT; ++t) {
    const int c = t & 1;
    const unsigned char* bA = smem + c * 57344;
    const unsigned char* bB = bA + 24576;
    bf16x8 af[6], bfv[4];

    // k-slice 0 fragment reads
    #pragma unroll
    for (int m = 0; m < 6; ++m)
      af[m] = *(const bf16x8*)(bA + swz(wm * 96 + m * 16 + lr, qk));
    #pragma unroll
    for (int n = 0; n < 4; ++n)
      bfv[n] = *(const bf16x8*)(bB + swz(wn * 64 + n * 16 + lr, qk));

    // stage tile t+1 into the other buffer; refill prefetch with tile t+2
    if (t < NIT - 1) { storeA(c ^ 1); storeB(c ^ 1); }
    if (t < NIT - 2) { issueA(t + 2); issueB(t + 2); }

    // k-slice 0 MFMAs
    #pragma unroll
    for (int m = 0; m < 6; ++m)
      #pragma unroll
      for (int n = 0; n < 4; ++n)
        acc[m][n] = __builtin_amdgcn_mfma_f32_16x16x32_bf16(af[m], bfv[n], acc[m][n], 0, 0, 0);

    // k-slice 1 fragment reads + MFMAs
    #pragma unroll
    for (int m = 0; m < 6; ++m)
      af[m] = *(const bf16x8*)(bA + swz(wm * 96 + m * 16 + lr, 64 + qk));
    #pragma unroll
    for (int n = 0; n < 4; ++n)
      bfv[n] = *(const bf16x8*)(bB + swz(wn * 64 + n * 16 + lr, 64 + qk));
    #pragma unroll
    for (int m = 0; m < 6; ++m)
      #pragma unroll
      for (int n = 0; n < 4; ++n)
        acc[m][n] = __builtin_amdgcn_mfma_f32_16x16x32_bf16(af[m], bfv[n], acc[m][n], 0, 0, 0);

    // single sync point: all reads retired (regs) + all writes visible
    asm volatile("s_waitcnt lgkmcnt(0)" ::: "memory");
    __builtin_amdgcn_s_barrier();
  }

  // ---- epilogue: bias + store. C/D: col=lane&15, row=(lane>>4)*4+reg ----
  float* po = out + (size_t)bb * DD * NCOL;
  const int g4 = (lane >> 4) * 4;
  #pragma unroll
  for (int m = 0; m < 6; ++m) {
    const int r0 = wm * 96 + m * 16 + g4;
    #pragma unroll
    for (int n = 0; n < 4; ++n) {
      const int col = wn * 64 + n * 16 + lr;
      #pragma unroll
      for (int j = 0; j < 4; ++j)
        po[(size_t)(bm0 + r0 + j) * NCOL + col] = acc[m][n][j] + bias_s[r0 + j];
    }
  }
}

extern "C" void kernel_launch(void* const* d_in, const int* in_sizes, int n_in,
                              void* d_out, int out_size, void* d_ws, size_t ws_size,
                              hipStream_t stream) {
  // inputs: 0:h_v(unused) 1:h_w 2:e_vw 3:We 4:be 5:Ww 6:bw
  const float* h_w  = (const float*)d_in[1];
  const float* e_vw = (const float*)d_in[2];
  const float* We   = (const float*)d_in[3];
  const float* be   = (const float*)d_in[4];
  const float* Ww   = (const float*)d_in[5];
  const float* bw   = (const float*)d_in[6];
  float* out = (float*)d_out;
  unsigned short* Wtile = (unsigned short*)d_ws;  // 147456 x 16B = 2.36 MB

  prep_w<<<dim3(576), 256, 0, stream>>>(We, Ww, Wtile);
  msg_kernel<<<dim3(512), 512, 0, stream>>>(h_w, e_vw, Wtile, be, bw, out);
}